// Round 13
// baseline (155.889 us; speedup 1.0000x reference)
//
#include <hip/hip_runtime.h>

typedef _Float16 f16;
typedef __attribute__((ext_vector_type(2))) _Float16 f16x2;
typedef __attribute__((ext_vector_type(4))) _Float16 f16x4;
typedef __attribute__((ext_vector_type(8))) _Float16 f16x8;
typedef __attribute__((ext_vector_type(4))) float    f32x4;
typedef __attribute__((ext_vector_type(16))) float   f32x16;
typedef __attribute__((ext_vector_type(4))) unsigned u32x4;

static constexpr int B_ = 2, N_ = 2048, E_ = 1024, H_ = 16, D_ = 64;
static constexpr int M_ = B_ * N_;   // 4096

#define MFMA16(a, b, c) __builtin_amdgcn_mfma_f32_16x16x32_f16(a, b, c, 0, 0, 0)
#define MFMA32(a, b, c) __builtin_amdgcn_mfma_f32_32x32x16_f16(a, b, c, 0, 0, 0)

// q-projection scale: 1/sqrt(D) * log2(e)  (softmax done in exp2 domain)
#define QSCALE 0.18033688011112042f

// async global(16B/lane) -> LDS (wave-uniform base + lane*16)
__device__ __forceinline__ void gload_lds16(const f16* g, f16* l) {
    typedef __attribute__((address_space(1))) const unsigned gu32;
    typedef __attribute__((address_space(3))) unsigned       lu32;
    __builtin_amdgcn_global_load_lds((gu32*)g, (lu32*)l, 16, 0, 0);
}

// ---------------------------------------------------------------------------
// Kernel 1: cast weights (4*E*E) AND q/k/v (3*M*E) fp32 -> f16 into one flat
// region: [Wq|Wk|Wv|Wo | q|k|v].
// ---------------------------------------------------------------------------
__global__ __launch_bounds__(256) void cast_all(
    const float* __restrict__ Wq, const float* __restrict__ Wk,
    const float* __restrict__ Wv, const float* __restrict__ Wo,
    const float* __restrict__ q, const float* __restrict__ k,
    const float* __restrict__ v, f16* __restrict__ dst)
{
    const int i = (blockIdx.x * 256 + threadIdx.x) * 4;
    const float* s;
    int j;
    if (i < 4 * E_ * E_) {
        const int which = i >> 20;                        // E*E = 2^20
        s = (which == 0) ? Wq : (which == 1) ? Wk : (which == 2) ? Wv : Wo;
        j = i & (E_ * E_ - 1);
    } else {
        const int t = i - 4 * E_ * E_;
        const int which = t >> 22;                        // M*E = 2^22
        s = (which == 0) ? q : (which == 1) ? k : v;
        j = t & (M_ * E_ - 1);
    }
    const f32x4 f = *(const f32x4*)&s[j];
    f16x4 o;
    o[0] = (f16)f[0]; o[1] = (f16)f[1]; o[2] = (f16)f[2]; o[3] = (f16)f[3];
    *(f16x4*)&dst[i] = o;
}

// ---------------------------------------------------------------------------
// Kernel 2: projection GEMM, m97-structure (global_load_lds, linear LDS,
//   XOR-chunk swizzle via pre-swizzled global source).  R6-proven version.
// ---------------------------------------------------------------------------
__global__ __launch_bounds__(256) void proj_gemm(
    const f16* __restrict__ Aall, const f16* __restrict__ Wb,
    const float* __restrict__ bq, const float* __restrict__ bk, const float* __restrict__ bv,
    f16* __restrict__ qh, f16* __restrict__ kh, f16* __restrict__ vt)
{
    const int bid  = blockIdx.x;
    const int lin  = (bid & 7) * 96 + (bid >> 3);
    const int z    = lin >> 8;
    const int rem  = lin & 255;
    const int m0   = (rem >> 3) * 128;
    const int n0   = (rem & 7) * 128;

    const f16* A    = Aall + (size_t)z * M_ * E_;
    const f16* W    = Wb + (size_t)z * E_ * E_;
    const float* bias = (z == 0) ? bq : (z == 1) ? bk : bv;

    __shared__ f16 As[128][32];
    __shared__ f16 Bs[128][32];

    const int tid  = threadIdx.x;
    const int lane = tid & 63, w = tid >> 6;
    const int lr = lane & 15, lg = lane >> 4;
    const int wm = (w >> 1) * 64, wn = (w & 1) * 64;

    const int gch = ((lane & 3) ^ ((lane >> 3) & 3)) * 8;
    const f16* ag = A + (size_t)(m0 + w * 32 + (lane >> 2)) * E_ + gch;
    const f16* bg = W + (size_t)(n0 + w * 32 + (lane >> 2)) * E_ + gch;
    f16* al0 = &As[w * 32][0];
    f16* al1 = &As[w * 32 + 16][0];
    f16* bl0 = &Bs[w * 32][0];
    f16* bl1 = &Bs[w * 32 + 16][0];

    const int ca = (lg ^ ((lr >> 1) & 3)) * 8;

    f32x4 acc[4][4];
#pragma unroll
    for (int i = 0; i < 4; i++)
#pragma unroll
        for (int j = 0; j < 4; j++) acc[i][j] = (f32x4){0.f, 0.f, 0.f, 0.f};

    for (int t = 0; t < E_ / 32; ++t) {
        __syncthreads();
        gload_lds16(ag,            al0);
        gload_lds16(ag + 16 * E_,  al1);
        gload_lds16(bg,            bl0);
        gload_lds16(bg + 16 * E_,  bl1);
        ag += 32; bg += 32;
        __syncthreads();

        f16x8 af[4], bfr[4];
#pragma unroll
        for (int ms = 0; ms < 4; ms++) af[ms]  = *(const f16x8*)&As[wm + ms * 16 + lr][ca];
#pragma unroll
        for (int ns = 0; ns < 4; ns++) bfr[ns] = *(const f16x8*)&Bs[wn + ns * 16 + lr][ca];
        __builtin_amdgcn_s_setprio(1);
#pragma unroll
        for (int ms = 0; ms < 4; ms++)
#pragma unroll
            for (int ns = 0; ns < 4; ns++)
                acc[ms][ns] = MFMA16(af[ms], bfr[ns], acc[ms][ns]);
        __builtin_amdgcn_s_setprio(0);
    }

    const float oscale = (z == 0) ? QSCALE : 1.0f;
#pragma unroll
    for (int ms = 0; ms < 4; ms++) {
        const int mbase = m0 + wm + ms * 16 + lg * 4;
#pragma unroll
        for (int ns = 0; ns < 4; ns++) {
            const int n  = n0 + wn + ns * 16 + lr;
            const float bn = bias[n];
            const int hh = n >> 6, dd = n & 63;
#pragma unroll
            for (int r = 0; r < 4; r++) {
                const float val = (acc[ms][ns][r] + bn) * oscale;
                const int mm = mbase + r;
                const int bb = mm >> 11;
                const int nn = mm & (N_ - 1);
                if (z == 2) {
                    vt[((size_t)(bb * H_ + hh) * D_ + dd) * N_ + nn] = (f16)val;
                } else {
                    f16* dst = (z == 0) ? qh : kh;
                    dst[((size_t)(bb * H_ + hh) * N_ + nn) * D_ + dd] = (f16)val;
                }
            }
        }
    }
}

// ---------------------------------------------------------------------------
// Kernel 3: flash attention — R6-proven body, kv-split x2 ACROSS blocks.
//  Grid 1024 = 32 bh x 16 qt x 2 kv-halves (XCD-swz, bh-major per XCD).
//  Each block: 16 rounds of 64 kv over its half; writes per-half normalized
//  O (f16) + (m,l) (f32) partials. 32KB LDS -> 4 blocks/CU.
// ---------------------------------------------------------------------------
__global__ __launch_bounds__(256) void attn_kernel(
    const f16* __restrict__ qh, const f16* __restrict__ kh,
    const f16* __restrict__ vt, f16* __restrict__ Op, float* __restrict__ ml)
{
    const int bid = blockIdx.x;
    const int lin = (bid & 7) * 128 + (bid >> 3);   // 1024 blocks, 8 XCDs
    const int bh  = lin >> 5;            // 0..31 (4 bh per XCD)
    const int rem = lin & 31;
    const int qt  = rem >> 1;            // 0..15
    const int kvh = rem & 1;             // kv half

    const int tid = threadIdx.x;
    const int w = tid >> 6, lane = tid & 63;
    const int l31 = lane & 31;
    const bool hi = (lane >> 5) != 0;
    const int hib = hi ? 1 : 0;

    const f16* qp = qh + (size_t)bh * N_ * D_;
    const f16* kp = kh + ((size_t)bh * N_ + kvh * 1024) * D_;
    const f16* vp = vt + (size_t)bh * D_ * N_ + kvh * 1024;

    const int qrow = qt * 128 + w * 32 + l31;

    f16x8 qf[4];
#pragma unroll
    for (int ks = 0; ks < 4; ks++)
        qf[ks] = *(const f16x8*)&qp[(size_t)qrow * D_ + ks * 16 + hib * 8];

    __shared__ f16 Ks[2][64][64];   // [buf][kv][d], swizzled
    __shared__ f16 Vs[2][64][64];   // [buf][d][kv], swizzled

    const int srow = tid >> 3;          // 0..31
    const int sch  = tid & 7;
    const int ssl  = (sch ^ (srow & 7)) * 8;

    const f16* kg0 = kp + (size_t)srow * D_ + sch * 8;
    const f16* kg1 = kg0 + (size_t)32 * D_;
    const f16* vg0 = vp + (size_t)srow * N_ + sch * 8;
    const f16* vg1 = vg0 + (size_t)32 * N_;

    f32x16 oT0 = {0.f,0.f,0.f,0.f,0.f,0.f,0.f,0.f,0.f,0.f,0.f,0.f,0.f,0.f,0.f,0.f};
    f32x16 oT1 = oT0;
    float mrun = -3.0e38f, lrun = 0.f;

    f16x8 kr0 = *(const f16x8*)(kg0);
    f16x8 kr1 = *(const f16x8*)(kg1);
    f16x8 vr0 = *(const f16x8*)(vg0);
    f16x8 vr1 = *(const f16x8*)(vg1);

    constexpr int NT = 1024 / 64;       // 16 rounds per half
    int cur = 0;

    for (int t = 0; t < NT; ++t) {
        *(f16x8*)&Ks[cur][srow     ][ssl] = kr0;
        *(f16x8*)&Ks[cur][srow + 32][ssl] = kr1;
        *(f16x8*)&Vs[cur][srow     ][ssl] = vr0;
        *(f16x8*)&Vs[cur][srow + 32][ssl] = vr1;
        if (t + 1 < NT) {
            kr0 = *(const f16x8*)(kg0 + (size_t)(t + 1) * 64 * D_);
            kr1 = *(const f16x8*)(kg1 + (size_t)(t + 1) * 64 * D_);
            vr0 = *(const f16x8*)(vg0 + (t + 1) * 64);
            vr1 = *(const f16x8*)(vg1 + (t + 1) * 64);
        }
        __syncthreads();

        // ---- S^T = K . Q^T ----
        f32x16 sA = {0.f,0.f,0.f,0.f,0.f,0.f,0.f,0.f,0.f,0.f,0.f,0.f,0.f,0.f,0.f,0.f};
        f32x16 sB = sA;
        __builtin_amdgcn_s_setprio(1);
#pragma unroll
        for (int ks = 0; ks < 4; ks++) {
            const int c = (ks * 2 + hib) ^ (l31 & 7);
            const f16x8 kfA = *(const f16x8*)&Ks[cur][l31     ][c * 8];
            const f16x8 kfB = *(const f16x8*)&Ks[cur][l31 + 32][c * 8];
            sA = MFMA32(kfA, qf[ks], sA);
            sB = MFMA32(kfB, qf[ks], sB);
        }
        __builtin_amdgcn_s_setprio(0);

        // ---- tile max (tree) + defer-max ----
        float t16[16];
#pragma unroll
        for (int r = 0; r < 16; r++) t16[r] = fmaxf(sA[r], sB[r]);
#pragma unroll
        for (int d = 8; d >= 1; d >>= 1)
#pragma unroll
            for (int r = 0; r < d; r++) t16[r] = fmaxf(t16[r], t16[r + d]);
        const float pmax = fmaxf(t16[0], __shfl_xor(t16[0], 32));

        if (!__all(pmax - mrun <= 8.0f)) {
            const float mnew = fmaxf(mrun, pmax);
            const float alpha = __builtin_amdgcn_exp2f(mrun - mnew);
            mrun = mnew;
            lrun *= alpha;
#pragma unroll
            for (int r = 0; r < 16; r++) { oT0[r] *= alpha; oT1[r] *= alpha; }
        }

        float p0 = 0.f, p1 = 0.f, p2 = 0.f, p3 = 0.f;
#pragma unroll
        for (int r = 0; r < 16; r += 4) {
            sA[r]   = __builtin_amdgcn_exp2f(sA[r]   - mrun); p0 += sA[r];
            sA[r+1] = __builtin_amdgcn_exp2f(sA[r+1] - mrun); p1 += sA[r+1];
            sA[r+2] = __builtin_amdgcn_exp2f(sA[r+2] - mrun); p2 += sA[r+2];
            sA[r+3] = __builtin_amdgcn_exp2f(sA[r+3] - mrun); p3 += sA[r+3];
        }
#pragma unroll
        for (int r = 0; r < 16; r += 4) {
            sB[r]   = __builtin_amdgcn_exp2f(sB[r]   - mrun); p0 += sB[r];
            sB[r+1] = __builtin_amdgcn_exp2f(sB[r+1] - mrun); p1 += sB[r+1];
            sB[r+2] = __builtin_amdgcn_exp2f(sB[r+2] - mrun); p2 += sB[r+2];
            sB[r+3] = __builtin_amdgcn_exp2f(sB[r+3] - mrun); p3 += sB[r+3];
        }
        float lsum = (p0 + p1) + (p2 + p3);
        lsum += __shfl_xor(lsum, 32);
        lrun += lsum;

        // ---- P -> B-frag via cvt_pkrtz + shfl_xor(32) + select (PROVEN) ----
        __builtin_amdgcn_s_setprio(1);
#define PVSTEP(PP0,PP1,PP2,PP3,PP4,PP5,PP6,PP7, KSI)                                   \
        {                                                                              \
            const unsigned w0 = __builtin_bit_cast(unsigned, __builtin_amdgcn_cvt_pkrtz(PP0, PP1)); \
            const unsigned w1 = __builtin_bit_cast(unsigned, __builtin_amdgcn_cvt_pkrtz(PP2, PP3)); \
            const unsigned w2 = __builtin_bit_cast(unsigned, __builtin_amdgcn_cvt_pkrtz(PP4, PP5)); \
            const unsigned w3 = __builtin_bit_cast(unsigned, __builtin_amdgcn_cvt_pkrtz(PP6, PP7)); \
            const unsigned x0 = (unsigned)__shfl_xor((int)w0, 32);                     \
            const unsigned x1 = (unsigned)__shfl_xor((int)w1, 32);                     \
            const unsigned x2 = (unsigned)__shfl_xor((int)w2, 32);                     \
            const unsigned x3 = (unsigned)__shfl_xor((int)w3, 32);                     \
            u32x4 pw;                                                                  \
            pw[0] = hi ? x2 : w0;                                                      \
            pw[1] = hi ? x3 : w1;                                                      \
            pw[2] = hi ? w2 : x0;                                                      \
            pw[3] = hi ? w3 : x1;                                                      \
            const f16x8 pa = __builtin_bit_cast(f16x8, pw);                            \
            const int c = ((KSI) * 2 + hib) ^ (l31 & 7);                               \
            const f16x8 vf0 = *(const f16x8*)&Vs[cur][l31     ][c * 8];                \
            const f16x8 vf1 = *(const f16x8*)&Vs[cur][l31 + 32][c * 8];                \
            oT0 = MFMA32(vf0, pa, oT0);                                                \
            oT1 = MFMA32(vf1, pa, oT1);                                                \
        }
        PVSTEP(sA[0],sA[1],sA[2],sA[3],sA[4],sA[5],sA[6],sA[7], 0)
        PVSTEP(sA[8],sA[9],sA[10],sA[11],sA[12],sA[13],sA[14],sA[15], 1)
        PVSTEP(sB[0],sB[1],sB[2],sB[3],sB[4],sB[5],sB[6],sB[7], 2)
        PVSTEP(sB[8],sB[9],sB[10],sB[11],sB[12],sB[13],sB[14],sB[15], 3)
#undef PVSTEP
        __builtin_amdgcn_s_setprio(0);

        cur ^= 1;
    }

    // ---- epilogue: per-half normalized O partial + (m,l) ----
    const float inv = 1.0f / lrun;
    const size_t prow = ((size_t)(kvh * 32 + bh) * N_ + qrow);
    f16* dst = Op + prow * D_ + hib * 4;
#pragma unroll
    for (int g = 0; g < 4; g++) {
        f16x4 o0, o1;
#pragma unroll
        for (int j = 0; j < 4; j++) {
            o0[j] = (f16)(oT0[g * 4 + j] * inv);
            o1[j] = (f16)(oT1[g * 4 + j] * inv);
        }
        *(f16x4*)&dst[8 * g]      = o0;
        *(f16x4*)&dst[8 * g + 32] = o1;
    }
    if (!hi) {
        ml[prow * 2]     = mrun;
        ml[prow * 2 + 1] = lrun;
    }
}

// ---------------------------------------------------------------------------
// Kernel 3b: merge the two kv-half partials into ao (f16 [B,N,E]).
//  thread -> (bh, qrow, d-octet).  524288 threads = 2048 x 256.
// ---------------------------------------------------------------------------
__global__ __launch_bounds__(256) void attn_merge(
    const f16* __restrict__ Op, const float* __restrict__ ml,
    f16* __restrict__ ao)
{
    const int t  = blockIdx.x * 256 + threadIdx.x;
    const int d8 = t & 7;
    const int qr = (t >> 3) & (N_ - 1);
    const int bh = t >> 14;

    const size_t r0 = (size_t)bh * N_ + qr;            // half 0 row
    const size_t r1 = (size_t)(32 + bh) * N_ + qr;     // half 1 row

    const float m0 = ml[r0 * 2], l0 = ml[r0 * 2 + 1];
    const float m1 = ml[r1 * 2], l1 = ml[r1 * 2 + 1];
    const float m  = fmaxf(m0, m1);
    const float w0 = l0 * __builtin_amdgcn_exp2f(m0 - m);
    const float w1 = l1 * __builtin_amdgcn_exp2f(m1 - m);
    const float s0 = w0 / (w0 + w1);
    const float s1 = 1.0f - s0;

    const f16x8 o0 = *(const f16x8*)&Op[r0 * D_ + d8 * 8];
    const f16x8 o1 = *(const f16x8*)&Op[r1 * D_ + d8 * 8];
    f16x8 o;
#pragma unroll
    for (int j = 0; j < 8; j++)
        o[j] = (f16)(s0 * (float)o0[j] + s1 * (float)o1[j]);

    const int b = bh >> 4, h = bh & 15;
    *(f16x8*)&ao[((size_t)(b * N_ + qr)) * E_ + h * 64 + d8 * 8] = o;
}

// ---------------------------------------------------------------------------
// Kernel 4: output GEMM, m97-structure.  out[m,n] = ao[m,:].Wo[n,:] + bo[n]
// ---------------------------------------------------------------------------
__global__ __launch_bounds__(256) void out_gemm(
    const f16* __restrict__ ao, const f16* __restrict__ Wo,
    const float* __restrict__ bo, float* __restrict__ out)
{
    __shared__ f16 As[128][32];
    __shared__ f16 Bs[128][32];

    const int bid = blockIdx.x;
    const int lin = (bid & 7) * 32 + (bid >> 3);
    const int m0  = (lin >> 3) * 128;
    const int n0  = (lin & 7) * 128;

    const int tid  = threadIdx.x;
    const int lane = tid & 63, w = tid >> 6;
    const int lr = lane & 15, lg = lane >> 4;
    const int wm = (w >> 1) * 64, wn = (w & 1) * 64;

    const int gch = ((lane & 3) ^ ((lane >> 3) & 3)) * 8;
    const f16* ag = ao + (size_t)(m0 + w * 32 + (lane >> 2)) * E_ + gch;
    const f16* bg = Wo + (size_t)(n0 + w * 32 + (lane >> 2)) * E_ + gch;
    f16* al0 = &As[w * 32][0];
    f16* al1 = &As[w * 32 + 16][0];
    f16* bl0 = &Bs[w * 32][0];
    f16* bl1 = &Bs[w * 32 + 16][0];

    const int ca = (lg ^ ((lr >> 1) & 3)) * 8;

    f32x4 acc[4][4];
#pragma unroll
    for (int i = 0; i < 4; i++)
#pragma unroll
        for (int j = 0; j < 4; j++) acc[i][j] = (f32x4){0.f, 0.f, 0.f, 0.f};

    for (int t = 0; t < E_ / 32; ++t) {
        __syncthreads();
        gload_lds16(ag,            al0);
        gload_lds16(ag + 16 * E_,  al1);
        gload_lds16(bg,            bl0);
        gload_lds16(bg + 16 * E_,  bl1);
        ag += 32; bg += 32;
        __syncthreads();

        f16x8 af[4], bfr[4];
#pragma unroll
        for (int ms = 0; ms < 4; ms++) af[ms]  = *(const f16x8*)&As[wm + ms * 16 + lr][ca];
#pragma unroll
        for (int ns = 0; ns < 4; ns++) bfr[ns] = *(const f16x8*)&Bs[wn + ns * 16 + lr][ca];
        __builtin_amdgcn_s_setprio(1);
#pragma unroll
        for (int ms = 0; ms < 4; ms++)
#pragma unroll
            for (int ns = 0; ns < 4; ns++)
                acc[ms][ns] = MFMA16(af[ms], bfr[ns], acc[ms][ns]);
        __builtin_amdgcn_s_setprio(0);
    }

#pragma unroll
    for (int ms = 0; ms < 4; ms++) {
        const int mbase = m0 + wm + ms * 16 + lg * 4;
#pragma unroll
        for (int ns = 0; ns < 4; ns++) {
            const int n = n0 + wn + ns * 16 + lr;
            const float bn = bo[n];
#pragma unroll
            for (int r = 0; r < 4; r++) {
                out[(size_t)(mbase + r) * E_ + n] = acc[ms][ns][r] + bn;
            }
        }
    }
}

// ---------------------------------------------------------------------------
extern "C" void kernel_launch(void* const* d_in, const int* in_sizes, int n_in,
                              void* d_out, int out_size, void* d_ws, size_t ws_size,
                              hipStream_t stream) {
    const float* q  = (const float*)d_in[0];
    const float* k  = (const float*)d_in[1];
    const float* v  = (const float*)d_in[2];
    const float* Wq = (const float*)d_in[3];
    const float* bq = (const float*)d_in[4];
    const float* Wk = (const float*)d_in[5];
    const float* bk = (const float*)d_in[6];
    const float* Wv = (const float*)d_in[7];
    const float* bv = (const float*)d_in[8];
    const float* Wo = (const float*)d_in[9];
    const float* bo = (const float*)d_in[10];
    float* out = (float*)d_out;

    char* ws = (char*)d_ws;
    f16* cast = (f16*)ws;                                  // [0,32MiB)
    f16* Wb   = cast;                                      // 0..8 MiB (kept for out_gemm)
    f16* Aall = cast + (size_t)4 * E_ * E_;                // 8..32 MiB (dead after proj)
    f16* qh = (f16*)(ws + (size_t)32 * 1024 * 1024);
    f16* kh = (f16*)(ws + (size_t)40 * 1024 * 1024);
    f16* vt = (f16*)(ws + (size_t)48 * 1024 * 1024);
    f16* ao = (f16*)(ws + (size_t)56 * 1024 * 1024);
    // partials overlay the dead Aall region (16 MiB + 1 MiB <= 24 MiB)
    f16*   Op = (f16*)(ws + (size_t)8 * 1024 * 1024);      // [2*32][N][64] f16 = 16 MiB
    float* ml = (float*)(ws + (size_t)24 * 1024 * 1024);   // [2*32][N]*2 f32 = 1 MiB

    cast_all<<<16384, 256, 0, stream>>>(Wq, Wk, Wv, Wo, q, k, v, cast);
    proj_gemm<<<768, 256, 0, stream>>>(Aall, Wb, bq, bk, bv, qh, kh, vt);
    attn_kernel<<<1024, 256, 0, stream>>>(qh, kh, vt, Op, ml);
    attn_merge<<<2048, 256, 0, stream>>>(Op, ml, ao);
    out_gemm<<<256, 256, 0, stream>>>(ao, Wb + (size_t)3 * E_ * E_, bo, out);
}

// Round 14
// 146.112 us; speedup vs baseline: 1.0669x; 1.0669x over previous
//
#include <hip/hip_runtime.h>

typedef _Float16 f16;
typedef __attribute__((ext_vector_type(2))) _Float16 f16x2;
typedef __attribute__((ext_vector_type(4))) _Float16 f16x4;
typedef __attribute__((ext_vector_type(8))) _Float16 f16x8;
typedef __attribute__((ext_vector_type(4))) float    f32x4;
typedef __attribute__((ext_vector_type(16))) float   f32x16;
typedef __attribute__((ext_vector_type(4))) unsigned u32x4;

static constexpr int B_ = 2, N_ = 2048, E_ = 1024, H_ = 16, D_ = 64;
static constexpr int M_ = B_ * N_;   // 4096

#define MFMA16(a, b, c) __builtin_amdgcn_mfma_f32_16x16x32_f16(a, b, c, 0, 0, 0)
#define MFMA32(a, b, c) __builtin_amdgcn_mfma_f32_32x32x16_f16(a, b, c, 0, 0, 0)

// q-projection scale: 1/sqrt(D) * log2(e)  (softmax done in exp2 domain)
#define QSCALE 0.18033688011112042f

// async global(16B/lane) -> LDS (wave-uniform base + lane*16)
__device__ __forceinline__ void gload_lds16(const f16* g, f16* l) {
    typedef __attribute__((address_space(1))) const unsigned gu32;
    typedef __attribute__((address_space(3))) unsigned       lu32;
    __builtin_amdgcn_global_load_lds((gu32*)g, (lu32*)l, 16, 0, 0);
}

// ---------------------------------------------------------------------------
// Kernel 1: cast the 4 weight matrices (fp32, [E,E] row-major) to f16.
// (q/k/v cast is fused into proj_gemm's A staging.)
// ---------------------------------------------------------------------------
__global__ __launch_bounds__(256) void castw_kernel(
    const float* __restrict__ Wq, const float* __restrict__ Wk,
    const float* __restrict__ Wv, const float* __restrict__ Wo,
    f16* __restrict__ dst)
{
    const int i = (blockIdx.x * 256 + threadIdx.x) * 4;
    const int which = i >> 20;                            // E*E = 2^20
    const float* s = (which == 0) ? Wq : (which == 1) ? Wk : (which == 2) ? Wv : Wo;
    const int j = i & (E_ * E_ - 1);
    const f32x4 f = *(const f32x4*)&s[j];
    f16x4 o;
    o[0] = (f16)f[0]; o[1] = (f16)f[1]; o[2] = (f16)f[2]; o[3] = (f16)f[3];
    *(f16x4*)&dst[i] = o;
}

// ---------------------------------------------------------------------------
// Kernel 2: projection GEMM. A = raw fp32 q/k/v, cast fused into reg-staged
//   A path (T14 prefetch: A(t+1) global loads issued before compute(t)).
//   B = f16 weights via gload_lds (m97 path, proven).
//   A LDS content map: As[row][pos] = chunk pos^(row&3)  (write-XOR swizzle,
//   bank-balanced both directions); read offset caA = (lg^(lr&3))*8.
//   Epilogue: q -> qh (scaled), k -> kh, v -> vt[b,h,d,n]  (R6-proven).
// ---------------------------------------------------------------------------
__global__ __launch_bounds__(256) void proj_gemm(
    const float* __restrict__ q, const float* __restrict__ k, const float* __restrict__ v,
    const f16* __restrict__ Wb,
    const float* __restrict__ bq, const float* __restrict__ bk, const float* __restrict__ bv,
    f16* __restrict__ qh, f16* __restrict__ kh, f16* __restrict__ vt)
{
    const int bid  = blockIdx.x;
    const int lin  = (bid & 7) * 96 + (bid >> 3);
    const int z    = lin >> 8;
    const int rem  = lin & 255;
    const int m0   = (rem >> 3) * 128;
    const int n0   = (rem & 7) * 128;

    const float* A    = (z == 0) ? q  : (z == 1) ? k  : v;   // fp32 [M][E]
    const f16*   W    = Wb + (size_t)z * E_ * E_;
    const float* bias = (z == 0) ? bq : (z == 1) ? bk : bv;

    __shared__ f16 As[128][32];
    __shared__ f16 Bs[128][32];

    const int tid  = threadIdx.x;
    const int lane = tid & 63, w = tid >> 6;
    const int lr = lane & 15, lg = lane >> 4;
    const int wm = (w >> 1) * 64, wn = (w & 1) * 64;

    // ---- B staging (unchanged, proven): pre-swizzled global + linear LDS ----
    const int gch = ((lane & 3) ^ ((lane >> 3) & 3)) * 8;
    const f16* bg = W + (size_t)(n0 + w * 32 + (lane >> 2)) * E_ + gch;
    f16* bl0 = &Bs[w * 32][0];
    f16* bl1 = &Bs[w * 32 + 16][0];

    // ---- A staging: thread -> row srow, half h; content chunk c = pos^(srow&3)
    const int srow = tid >> 1;            // 0..127
    const int h    = tid & 1;             // half-row
    const int s3   = srow & 3;
    const int c0   = (2 * h)     ^ s3;    // global chunk stored at pos 2h
    const int c1   = (2 * h + 1) ^ s3;    // global chunk stored at pos 2h+1
    const float* ag = A + (size_t)(m0 + srow) * E_;

    const int caA = (lg ^ (lr & 3)) * 8;         // A read chunk (new map)
    const int caB = (lg ^ ((lr >> 1) & 3)) * 8;  // B read chunk (proven map)

    f32x4 acc[4][4];
#pragma unroll
    for (int i = 0; i < 4; i++)
#pragma unroll
        for (int j = 0; j < 4; j++) acc[i][j] = (f32x4){0.f, 0.f, 0.f, 0.f};

    // prologue: A(0) into regs
    f32x4 aA0 = *(const f32x4*)(ag + 8 * c0);
    f32x4 aA1 = *(const f32x4*)(ag + 8 * c0 + 4);
    f32x4 aB0 = *(const f32x4*)(ag + 8 * c1);
    f32x4 aB1 = *(const f32x4*)(ag + 8 * c1 + 4);

    for (int t = 0; t < E_ / 32; ++t) {
        __syncthreads();                       // prev iter's LDS reads done
        gload_lds16(bg,           bl0);
        gload_lds16(bg + 16 * E_, bl1);
        bg += 32;
        {
            f16x8 w0, w1;
#pragma unroll
            for (int j = 0; j < 4; j++) {
                w0[j] = (f16)aA0[j]; w0[4 + j] = (f16)aA1[j];
                w1[j] = (f16)aB0[j]; w1[4 + j] = (f16)aB1[j];
            }
            *(f16x8*)&As[srow][16 * h]     = w0;
            *(f16x8*)&As[srow][16 * h + 8] = w1;
        }
        if (t + 1 < E_ / 32) {                 // prefetch A(t+1): hides under compute
            const float* an = ag + (t + 1) * 32;
            aA0 = *(const f32x4*)(an + 8 * c0);
            aA1 = *(const f32x4*)(an + 8 * c0 + 4);
            aB0 = *(const f32x4*)(an + 8 * c1);
            aB1 = *(const f32x4*)(an + 8 * c1 + 4);
        }
        __syncthreads();                       // staged data visible

        f16x8 af[4], bfr[4];
#pragma unroll
        for (int ms = 0; ms < 4; ms++) af[ms]  = *(const f16x8*)&As[wm + ms * 16 + lr][caA];
#pragma unroll
        for (int ns = 0; ns < 4; ns++) bfr[ns] = *(const f16x8*)&Bs[wn + ns * 16 + lr][caB];
        __builtin_amdgcn_s_setprio(1);
#pragma unroll
        for (int ms = 0; ms < 4; ms++)
#pragma unroll
            for (int ns = 0; ns < 4; ns++)
                acc[ms][ns] = MFMA16(af[ms], bfr[ns], acc[ms][ns]);
        __builtin_amdgcn_s_setprio(0);
    }

    const float oscale = (z == 0) ? QSCALE : 1.0f;
#pragma unroll
    for (int ms = 0; ms < 4; ms++) {
        const int mbase = m0 + wm + ms * 16 + lg * 4;
#pragma unroll
        for (int ns = 0; ns < 4; ns++) {
            const int n  = n0 + wn + ns * 16 + lr;
            const float bn = bias[n];
            const int hh = n >> 6, dd = n & 63;
#pragma unroll
            for (int r = 0; r < 4; r++) {
                const float val = (acc[ms][ns][r] + bn) * oscale;
                const int mm = mbase + r;
                const int bb = mm >> 11;
                const int nn = mm & (N_ - 1);
                if (z == 2) {
                    vt[((size_t)(bb * H_ + hh) * D_ + dd) * N_ + nn] = (f16)val;
                } else {
                    f16* dst = (z == 0) ? qh : kh;
                    dst[((size_t)(bb * H_ + hh) * N_ + nn) * D_ + dd] = (f16)val;
                }
            }
        }
    }
}

// ---------------------------------------------------------------------------
// Kernel 3: flash attention — R6/R12-proven (grid 512, 4 waves, reg-staged
//  dbuf K/V with XOR ds_write swizzle, defer-max, shfl_xor cross-half).
// ---------------------------------------------------------------------------
__global__ __launch_bounds__(256) void attn_kernel(
    const f16* __restrict__ qh, const f16* __restrict__ kh,
    const f16* __restrict__ vt, f16* __restrict__ ao)
{
    const int bid = blockIdx.x;
    const int swz = (bid & 7) * 64 + (bid >> 3);   // 512 blocks, 8 XCDs
    const int qt = swz & 15;            // 16 q-tiles of 128 rows
    const int bh = swz >> 4;            // 0..31

    const int tid = threadIdx.x;
    const int w = tid >> 6, lane = tid & 63;
    const int l31 = lane & 31;
    const bool hi = (lane >> 5) != 0;
    const int hib = hi ? 1 : 0;

    const f16* qp = qh + (size_t)bh * N_ * D_;
    const f16* kp = kh + (size_t)bh * N_ * D_;
    const f16* vp = vt + (size_t)bh * D_ * N_;

    const int qrow = qt * 128 + w * 32 + l31;

    f16x8 qf[4];
#pragma unroll
    for (int ks = 0; ks < 4; ks++)
        qf[ks] = *(const f16x8*)&qp[(size_t)qrow * D_ + ks * 16 + hib * 8];

    __shared__ f16 Ks[2][64][64];   // [kv][d], swizzled
    __shared__ f16 Vs[2][64][64];   // [d][kv], swizzled

    const int srow = tid >> 3;          // 0..31
    const int sch  = tid & 7;
    const int ssl  = (sch ^ (srow & 7)) * 8;

    const f16* kg0 = kp + (size_t)srow * D_ + sch * 8;
    const f16* kg1 = kg0 + (size_t)32 * D_;
    const f16* vg0 = vp + (size_t)srow * N_ + sch * 8;
    const f16* vg1 = vg0 + (size_t)32 * N_;

    f32x16 oT0 = {0.f,0.f,0.f,0.f,0.f,0.f,0.f,0.f,0.f,0.f,0.f,0.f,0.f,0.f,0.f,0.f};
    f32x16 oT1 = oT0;
    float mrun = -3.0e38f, lrun = 0.f;

    f16x8 kr0 = *(const f16x8*)(kg0);
    f16x8 kr1 = *(const f16x8*)(kg1);
    f16x8 vr0 = *(const f16x8*)(vg0);
    f16x8 vr1 = *(const f16x8*)(vg1);

    constexpr int NT = N_ / 64;         // 32
    int cur = 0;

    for (int t = 0; t < NT; ++t) {
        *(f16x8*)&Ks[cur][srow     ][ssl] = kr0;
        *(f16x8*)&Ks[cur][srow + 32][ssl] = kr1;
        *(f16x8*)&Vs[cur][srow     ][ssl] = vr0;
        *(f16x8*)&Vs[cur][srow + 32][ssl] = vr1;
        if (t + 1 < NT) {
            kr0 = *(const f16x8*)(kg0 + (size_t)(t + 1) * 64 * D_);
            kr1 = *(const f16x8*)(kg1 + (size_t)(t + 1) * 64 * D_);
            vr0 = *(const f16x8*)(vg0 + (t + 1) * 64);
            vr1 = *(const f16x8*)(vg1 + (t + 1) * 64);
        }
        __syncthreads();

        // ---- S^T = K . Q^T ----
        f32x16 sA = {0.f,0.f,0.f,0.f,0.f,0.f,0.f,0.f,0.f,0.f,0.f,0.f,0.f,0.f,0.f,0.f};
        f32x16 sB = sA;
        __builtin_amdgcn_s_setprio(1);
#pragma unroll
        for (int ks = 0; ks < 4; ks++) {
            const int c = (ks * 2 + hib) ^ (l31 & 7);
            const f16x8 kfA = *(const f16x8*)&Ks[cur][l31     ][c * 8];
            const f16x8 kfB = *(const f16x8*)&Ks[cur][l31 + 32][c * 8];
            sA = MFMA32(kfA, qf[ks], sA);
            sB = MFMA32(kfB, qf[ks], sB);
        }
        __builtin_amdgcn_s_setprio(0);

        // ---- tile max (tree) + defer-max ----
        float t16[16];
#pragma unroll
        for (int r = 0; r < 16; r++) t16[r] = fmaxf(sA[r], sB[r]);
#pragma unroll
        for (int d = 8; d >= 1; d >>= 1)
#pragma unroll
            for (int r = 0; r < d; r++) t16[r] = fmaxf(t16[r], t16[r + d]);
        const float pmax = fmaxf(t16[0], __shfl_xor(t16[0], 32));

        if (!__all(pmax - mrun <= 8.0f)) {
            const float mnew = fmaxf(mrun, pmax);
            const float alpha = __builtin_amdgcn_exp2f(mrun - mnew);
            mrun = mnew;
            lrun *= alpha;
#pragma unroll
            for (int r = 0; r < 16; r++) { oT0[r] *= alpha; oT1[r] *= alpha; }
        }

        float p0 = 0.f, p1 = 0.f, p2 = 0.f, p3 = 0.f;
#pragma unroll
        for (int r = 0; r < 16; r += 4) {
            sA[r]   = __builtin_amdgcn_exp2f(sA[r]   - mrun); p0 += sA[r];
            sA[r+1] = __builtin_amdgcn_exp2f(sA[r+1] - mrun); p1 += sA[r+1];
            sA[r+2] = __builtin_amdgcn_exp2f(sA[r+2] - mrun); p2 += sA[r+2];
            sA[r+3] = __builtin_amdgcn_exp2f(sA[r+3] - mrun); p3 += sA[r+3];
        }
#pragma unroll
        for (int r = 0; r < 16; r += 4) {
            sB[r]   = __builtin_amdgcn_exp2f(sB[r]   - mrun); p0 += sB[r];
            sB[r+1] = __builtin_amdgcn_exp2f(sB[r+1] - mrun); p1 += sB[r+1];
            sB[r+2] = __builtin_amdgcn_exp2f(sB[r+2] - mrun); p2 += sB[r+2];
            sB[r+3] = __builtin_amdgcn_exp2f(sB[r+3] - mrun); p3 += sB[r+3];
        }
        float lsum = (p0 + p1) + (p2 + p3);
        lsum += __shfl_xor(lsum, 32);
        lrun += lsum;

        // ---- P -> B-frag via cvt_pkrtz + shfl_xor(32) + select (PROVEN) ----
        __builtin_amdgcn_s_setprio(1);
#define PVSTEP(PP0,PP1,PP2,PP3,PP4,PP5,PP6,PP7, KSI)                                   \
        {                                                                              \
            const unsigned w0 = __builtin_bit_cast(unsigned, __builtin_amdgcn_cvt_pkrtz(PP0, PP1)); \
            const unsigned w1 = __builtin_bit_cast(unsigned, __builtin_amdgcn_cvt_pkrtz(PP2, PP3)); \
            const unsigned w2 = __builtin_bit_cast(unsigned, __builtin_amdgcn_cvt_pkrtz(PP4, PP5)); \
            const unsigned w3 = __builtin_bit_cast(unsigned, __builtin_amdgcn_cvt_pkrtz(PP6, PP7)); \
            const unsigned x0 = (unsigned)__shfl_xor((int)w0, 32);                     \
            const unsigned x1 = (unsigned)__shfl_xor((int)w1, 32);                     \
            const unsigned x2 = (unsigned)__shfl_xor((int)w2, 32);                     \
            const unsigned x3 = (unsigned)__shfl_xor((int)w3, 32);                     \
            u32x4 pw;                                                                  \
            pw[0] = hi ? x2 : w0;                                                      \
            pw[1] = hi ? x3 : w1;                                                      \
            pw[2] = hi ? w2 : x0;                                                      \
            pw[3] = hi ? w3 : x1;                                                      \
            const f16x8 pa = __builtin_bit_cast(f16x8, pw);                            \
            const int c = ((KSI) * 2 + hib) ^ (l31 & 7);                               \
            const f16x8 vf0 = *(const f16x8*)&Vs[cur][l31     ][c * 8];                \
            const f16x8 vf1 = *(const f16x8*)&Vs[cur][l31 + 32][c * 8];                \
            oT0 = MFMA32(vf0, pa, oT0);                                                \
            oT1 = MFMA32(vf1, pa, oT1);                                                \
        }
        PVSTEP(sA[0],sA[1],sA[2],sA[3],sA[4],sA[5],sA[6],sA[7], 0)
        PVSTEP(sA[8],sA[9],sA[10],sA[11],sA[12],sA[13],sA[14],sA[15], 1)
        PVSTEP(sB[0],sB[1],sB[2],sB[3],sB[4],sB[5],sB[6],sB[7], 2)
        PVSTEP(sB[8],sB[9],sB[10],sB[11],sB[12],sB[13],sB[14],sB[15], 3)
#undef PVSTEP
        __builtin_amdgcn_s_setprio(0);

        cur ^= 1;
    }

    // ---- epilogue: O[q][d] = O^T / lrun ----
    const float inv = 1.0f / lrun;
    const int b = bh >> 4, h = bh & 15;
    f16* dst = ao + (size_t)(b * N_ + qrow) * E_ + h * 64 + hib * 4;
#pragma unroll
    for (int g = 0; g < 4; g++) {
        f16x4 o0, o1;
#pragma unroll
        for (int j = 0; j < 4; j++) {
            o0[j] = (f16)(oT0[g * 4 + j] * inv);
            o1[j] = (f16)(oT1[g * 4 + j] * inv);
        }
        *(f16x4*)&dst[8 * g]      = o0;
        *(f16x4*)&dst[8 * g + 32] = o1;
    }
}

// ---------------------------------------------------------------------------
// Kernel 4: output GEMM, m97-structure.  out[m,n] = ao[m,:].Wo[n,:] + bo[n]
// ---------------------------------------------------------------------------
__global__ __launch_bounds__(256) void out_gemm(
    const f16* __restrict__ ao, const f16* __restrict__ Wo,
    const float* __restrict__ bo, float* __restrict__ out)
{
    __shared__ f16 As[128][32];
    __shared__ f16 Bs[128][32];

    const int bid = blockIdx.x;
    const int lin = (bid & 7) * 32 + (bid >> 3);
    const int m0  = (lin >> 3) * 128;
    const int n0  = (lin & 7) * 128;

    const int tid  = threadIdx.x;
    const int lane = tid & 63, w = tid >> 6;
    const int lr = lane & 15, lg = lane >> 4;
    const int wm = (w >> 1) * 64, wn = (w & 1) * 64;

    const int gch = ((lane & 3) ^ ((lane >> 3) & 3)) * 8;
    const f16* ag = ao + (size_t)(m0 + w * 32 + (lane >> 2)) * E_ + gch;
    const f16* bg = Wo + (size_t)(n0 + w * 32 + (lane >> 2)) * E_ + gch;
    f16* al0 = &As[w * 32][0];
    f16* al1 = &As[w * 32 + 16][0];
    f16* bl0 = &Bs[w * 32][0];
    f16* bl1 = &Bs[w * 32 + 16][0];

    const int ca = (lg ^ ((lr >> 1) & 3)) * 8;

    f32x4 acc[4][4];
#pragma unroll
    for (int i = 0; i < 4; i++)
#pragma unroll
        for (int j = 0; j < 4; j++) acc[i][j] = (f32x4){0.f, 0.f, 0.f, 0.f};

    for (int t = 0; t < E_ / 32; ++t) {
        __syncthreads();
        gload_lds16(ag,            al0);
        gload_lds16(ag + 16 * E_,  al1);
        gload_lds16(bg,            bl0);
        gload_lds16(bg + 16 * E_,  bl1);
        ag += 32; bg += 32;
        __syncthreads();

        f16x8 af[4], bfr[4];
#pragma unroll
        for (int ms = 0; ms < 4; ms++) af[ms]  = *(const f16x8*)&As[wm + ms * 16 + lr][ca];
#pragma unroll
        for (int ns = 0; ns < 4; ns++) bfr[ns] = *(const f16x8*)&Bs[wn + ns * 16 + lr][ca];
        __builtin_amdgcn_s_setprio(1);
#pragma unroll
        for (int ms = 0; ms < 4; ms++)
#pragma unroll
            for (int ns = 0; ns < 4; ns++)
                acc[ms][ns] = MFMA16(af[ms], bfr[ns], acc[ms][ns]);
        __builtin_amdgcn_s_setprio(0);
    }

#pragma unroll
    for (int ms = 0; ms < 4; ms++) {
        const int mbase = m0 + wm + ms * 16 + lg * 4;
#pragma unroll
        for (int ns = 0; ns < 4; ns++) {
            const int n = n0 + wn + ns * 16 + lr;
            const float bn = bo[n];
#pragma unroll
            for (int r = 0; r < 4; r++) {
                out[(size_t)(mbase + r) * E_ + n] = acc[ms][ns][r] + bn;
            }
        }
    }
}

// ---------------------------------------------------------------------------
extern "C" void kernel_launch(void* const* d_in, const int* in_sizes, int n_in,
                              void* d_out, int out_size, void* d_ws, size_t ws_size,
                              hipStream_t stream) {
    const float* q  = (const float*)d_in[0];
    const float* k  = (const float*)d_in[1];
    const float* v  = (const float*)d_in[2];
    const float* Wq = (const float*)d_in[3];
    const float* bq = (const float*)d_in[4];
    const float* Wk = (const float*)d_in[5];
    const float* bk = (const float*)d_in[6];
    const float* Wv = (const float*)d_in[7];
    const float* bv = (const float*)d_in[8];
    const float* Wo = (const float*)d_in[9];
    const float* bo = (const float*)d_in[10];
    float* out = (float*)d_out;

    char* ws = (char*)d_ws;
    f16* Wb = (f16*)ws;                                   //  8 MB: Wq|Wk|Wv|Wo f16
    f16* qh = (f16*)(ws + (size_t)32 * 1024 * 1024);
    f16* kh = (f16*)(ws + (size_t)40 * 1024 * 1024);
    f16* vt = (f16*)(ws + (size_t)48 * 1024 * 1024);
    f16* ao = (f16*)(ws + (size_t)56 * 1024 * 1024);

    castw_kernel<<<4096, 256, 0, stream>>>(Wq, Wk, Wv, Wo, Wb);
    proj_gemm<<<768, 256, 0, stream>>>(q, k, v, Wb, bq, bk, bv, qh, kh, vt);
    attn_kernel<<<512, 256, 0, stream>>>(qh, kh, vt, ao);
    out_gemm<<<256, 256, 0, stream>>>(ao, Wb + (size_t)3 * E_ * E_, bo, out);
}